// Round 13
// baseline (1327.525 us; speedup 1.0000x reference)
//
#include <hip/hip_runtime.h>

typedef __attribute__((ext_vector_type(8))) short short8;
typedef __attribute__((ext_vector_type(4))) float f32x4;
typedef _Float16 half_t;

__device__ __forceinline__ unsigned short f2bf(float x){
  union { float f; unsigned u; } v; v.f = x;
  unsigned r = v.u + 0x7fffu + ((v.u >> 16) & 1u);
  return (unsigned short)(r >> 16);
}
__device__ __forceinline__ float sigm(float x){ return 1.0f / (1.0f + __expf(-x)); }
__device__ __forceinline__ float tanh_(float x){
  float e = __expf(2.0f * x);
  return 1.0f - 2.0f / (e + 1.0f);
}
__device__ __forceinline__ short8 load_bf8_f32(const float* p){
  float4 a = *(const float4*)p;
  float4 b = *(const float4*)(p + 4);
  short8 r;
  r[0]=(short)f2bf(a.x); r[1]=(short)f2bf(a.y); r[2]=(short)f2bf(a.z); r[3]=(short)f2bf(a.w);
  r[4]=(short)f2bf(b.x); r[5]=(short)f2bf(b.y); r[6]=(short)f2bf(b.z); r[7]=(short)f2bf(b.w);
  return r;
}
__device__ __forceinline__ f32x4 mfma16(short8 a, short8 b, f32x4 c){
  return __builtin_amdgcn_mfma_f32_16x16x32_bf16(a, b, c, 0, 0, 0);
}
__device__ __forceinline__ void gload16(const void* g, void* lds){
  __builtin_amdgcn_global_load_lds((const __attribute__((address_space(1))) void*)g,
                                   (__attribute__((address_space(3))) void*)lds, 16, 0, 0);
}
__device__ __forceinline__ f32x4 shfl_xor4(f32x4 v, int m){
  f32x4 r;
  r[0]=__shfl_xor(v[0],m); r[1]=__shfl_xor(v[1],m);
  r[2]=__shfl_xor(v[2],m); r[3]=__shfl_xor(v[3],m);
  return r;
}
__device__ __forceinline__ float pick4(f32x4 v, int k){
  float a = (k&1)? v[1] : v[0];
  float b = (k&1)? v[3] : v[2];
  return (k&2)? b : a;
}
__device__ __forceinline__ f32x4 sel4(f32x4 a0, f32x4 a1, f32x4 a2, f32x4 a3, int k){
  f32x4 x = (k&1)? a1 : a0;
  f32x4 y = (k&1)? a3 : a2;
  return (k&2)? y : x;
}

// ======= 128x128 MFMA GEMM K-loop: single-buffer 2-barrier (m97) + XOR swizzle =======
#define KSTAGE1(AB, BB, off)                                                         \
  {                                                                                  \
    _Pragma("unroll")                                                                \
    for (int q = 0; q < 4; ++q){                                                     \
      gload16(AB[q] + (off), As + (q*32 + w*8)*64);                                  \
      gload16(BB[q] + (off), Bs + (q*32 + w*8)*64);                                  \
    }                                                                                \
  }

#define KCOMP1                                                                       \
  {                                                                                  \
    _Pragma("unroll")                                                                \
    for (int kk = 0; kk < 2; ++kk){                                                  \
      short8 av[4], bv[4];                                                           \
      _Pragma("unroll")                                                              \
      for (int i = 0; i < 4; ++i)                                                    \
        av[i] = *(const short8*)&As[(wm*64 + i*16 + r15)*64 + (((kk*4 + g4) ^ (r15 & 7))*8)]; \
      _Pragma("unroll")                                                              \
      for (int i = 0; i < 4; ++i)                                                    \
        bv[i] = *(const short8*)&Bs[(wn*64 + i*16 + r15)*64 + (((kk*4 + g4) ^ (r15 & 7))*8)]; \
      _Pragma("unroll")                                                              \
      for (int i = 0; i < 4; ++i)                                                    \
        _Pragma("unroll")                                                            \
        for (int j = 0; j < 4; ++j) acc[i][j] = mfma16(av[i], bv[j], acc[i][j]);     \
    }                                                                                \
  }

#define KLOOP1(AB, BB)                                                               \
  for (int kt = 0; kt < 8; ++kt){                                                    \
    KSTAGE1(AB, BB, kt*64)                                                           \
    __syncthreads();                                                                 \
    KCOMP1                                                                           \
    __syncthreads();                                                                 \
  }

// ---------------- prep: converts, remaps, transpose, bias folds, sorts ----------------
__global__ __launch_bounds__(256) void prep_kernel(
    const float* __restrict__ emb, const int* __restrict__ dep,
    const float* __restrict__ W_dep, const float* __restrict__ b_dep,
    const float* __restrict__ W_ih, const float* __restrict__ W_hh,
    const float* __restrict__ b_ih, const float* __restrict__ b_hh,
    unsigned short* __restrict__ embb, unsigned short* __restrict__ Wih_il,
    unsigned short* __restrict__ Whh_il, unsigned short* __restrict__ Wleaf,
    unsigned short* __restrict__ WdT, float* __restrict__ bsum, float* __restrict__ bc,
    int* __restrict__ perm, int* __restrict__ tile_p, int* __restrict__ meta,
    int* __restrict__ perm16, int* __restrict__ tile16, int* __restrict__ meta16)
{
  const int bid = blockIdx.x, tid = threadIdx.x;
  if (bid < 1024){
    for (size_t i = (size_t)bid*256 + tid; i < 2396736ull; i += 1024ull*256)
      *(short8*)(embb + i*8) = load_bf8_f32(emb + i*8);
  } else if (bid < 1536){
    int idx = (bid-1024)*256 + tid; int r = idx >> 6, c8 = idx & 63;
    int sr = (r & 3)*512 + (r >> 2);
    *(short8*)(Wih_il + (size_t)r*512 + c8*8) = load_bf8_f32(W_ih + (size_t)sr*512 + c8*8);
  } else if (bid < 2048){
    int idx = (bid-1536)*256 + tid; int r = idx >> 6, c8 = idx & 63;
    int sr = (r & 3)*512 + (r >> 2);
    *(short8*)(Whh_il + (size_t)r*512 + c8*8) = load_bf8_f32(W_hh + (size_t)sr*512 + c8*8);
  } else if (bid < 2304){
    int idx = (bid-2048)*256 + tid; int r = idx >> 6, c8 = idx & 63;
    int sr = ((r & 1) ? 2 : 0)*512 + (r >> 1);
    *(short8*)(Wleaf + (size_t)r*512 + c8*8) = load_bf8_f32(W_ih + (size_t)sr*512 + c8*8);
  } else if (bid < 2816){
    __shared__ unsigned short tle[64][65];
    int lb = bid - 2304; int p = lb >> 6; int tile = lb & 63;
    int i0 = (tile >> 3)*64, j0 = (tile & 7)*64;
    const float* src = W_dep + (size_t)p*512*512;
    for (int q = 0; q < 16; ++q){
      int e = q*256 + tid; int li = e >> 6, lj = e & 63;
      tle[li][lj] = f2bf(src[(size_t)(i0+li)*512 + (j0+lj)]);
    }
    __syncthreads();
    unsigned short* dst = WdT + (size_t)p*512*512;
    for (int q = 0; q < 16; ++q){
      int e = q*256 + tid; int lj = e >> 6, li = e & 63;
      dst[(size_t)(j0+lj)*512 + (i0+li)] = tle[li][lj];
    }
  } else if (bid < 2824){
    int r = (bid-2816)*256 + tid;
    if (r < 2048){ int g = r & 3, j = r >> 2; bsum[r] = b_ih[g*512+j] + b_hh[g*512+j]; }
  } else if (bid < 2888){
    __shared__ float bd[512];
    int lb = bid - 2824; int p = lb >> 3, ch = lb & 7;
    for (int i = tid; i < 512; i += 256) bd[i] = b_dep[p*512 + i];
    __syncthreads();
    int r = ch*256 + tid; int g = r & 3, j = r >> 2;
    const float* wr = W_ih + (size_t)(g*512 + j)*512;
    float s = 0.0f;
    for (int i = 0; i < 512; ++i) s = fmaf(wr[i], bd[i], s);
    bc[(size_t)p*2048 + r] = s;
  } else if (bid < 2928){
    __shared__ int cnt[8], base[8], fill[8];
    int lb = bid - 2888; const int l = lb >> 3, t = lb & 7;
    const int M_[5]  = {1,8,64,512,4096};
    const int CB_[5] = {1,9,73,585,4681};
    const int MT_[5] = {8,8,8,12,40};
    const int PB_[5] = {69632,61440,53248,40960,0};
    const int TB_[5] = {544,480,416,320,0};
    const int m = M_[l], cb = CB_[l], MT = MT_[l];
    int* pm = perm + PB_[l] + t*MT*128;
    int* tp = tile_p + TB_[l] + t*MT;
    if (tid < 8){ cnt[tid] = 0; fill[tid] = 0; }
    __syncthreads();
    for (int n = tid; n < m; n += 256) atomicAdd(&cnt[dep[cb + n*8 + t]], 1);
    __syncthreads();
    if (tid == 0){
      int tiles = 0;
      for (int p = 0; p < 8; ++p){
        base[p] = tiles*128;
        int g = (cnt[p] + 127) >> 7;
        for (int q = 0; q < g; ++q) tp[tiles + q] = p;
        tiles += g;
      }
      meta[l*8 + t] = tiles;
    }
    __syncthreads();
    for (int i = tid; i < MT*128; i += 256) pm[i] = -1;
    __syncthreads();
    for (int n = tid; n < m; n += 256){
      int p = dep[cb + n*8 + t];
      pm[base[p] + atomicAdd(&fill[p], 1)] = n;
    }
  } else {
    // 16-row type-group sort for levels 3..0 (li: 0=l3, 1=l2, 2=l1, 3=l0)
    __shared__ int cnt[8], base[8], fill[8];
    int lb = bid - 2928; const int li = lb >> 3, t = lb & 7;
    const int M_[4]  = {512,64,8,1};
    const int CB_[4] = {585,73,9,1};
    const int MT_[4] = {40,8,8,8};
    const int PB_[4] = {0, 5120, 6144, 7168};
    const int TB_[4] = {0, 320, 384, 448};
    const int m = M_[li], cbb = CB_[li], MT = MT_[li];
    int* pm = perm16 + PB_[li] + t*MT*16;
    int* tp = tile16 + TB_[li] + t*MT;
    if (tid < 8){ cnt[tid] = 0; fill[tid] = 0; }
    __syncthreads();
    for (int n = tid; n < m; n += 256) atomicAdd(&cnt[dep[cbb + n*8 + t]], 1);
    __syncthreads();
    if (tid == 0){
      int tiles = 0;
      for (int p = 0; p < 8; ++p){
        base[p] = tiles*16;
        int g = (cnt[p] + 15) >> 4;
        for (int q = 0; q < g; ++q) tp[tiles + q] = p;
        tiles += g;
      }
      meta16[li*8 + t] = tiles;
    }
    __syncthreads();
    for (int i = tid; i < MT*16; i += 256) pm[i] = -1;
    __syncthreads();
    for (int n = tid; n < m; n += 256){
      int p = dep[cbb + n*8 + t];
      pm[base[p] + atomicAdd(&fill[p], 1)] = n;
    }
  }
}

// ---- fused one-time GEMMs: Wcombo (jobs 0..511) + leaf (jobs 512..2559) ----
__global__ __launch_bounds__(256) void comboleaf_kernel(
    const unsigned short* __restrict__ Wih_il,
    const unsigned short* __restrict__ WdT,
    unsigned short* __restrict__ Wcombo,
    const unsigned short* __restrict__ embL,
    const unsigned short* __restrict__ Wleaf,
    const float* __restrict__ bsum,
    unsigned short* __restrict__ zo)
{
  __shared__ unsigned short As[8192];
  __shared__ unsigned short Bs[8192];
  const int tid = threadIdx.x, lane = tid & 63, w = tid >> 6;
  const int wm = w >> 1, wn = w & 1;
  const int r15 = lane & 15, g4 = lane >> 4;
  const int kc = ((lane & 7) ^ (lane >> 3)) * 8;

  if (blockIdx.x < 512){
    const int p  = blockIdx.x >> 6;
    const int mt = (blockIdx.x >> 2) & 15;
    const int nb = blockIdx.x & 3;
    const unsigned short* ab[4]; const unsigned short* bb[4];
    #pragma unroll
    for (int q = 0; q < 4; ++q){
      int rl = mt*128 + q*32 + w*8 + (lane >> 3);
      ab[q] = Wih_il + (size_t)rl*512 + kc;
      int br = nb*128 + q*32 + w*8 + (lane >> 3);
      bb[q] = WdT + (size_t)p*262144 + (size_t)br*512 + kc;
    }
    f32x4 acc[4][4] = {};
    KLOOP1(ab, bb)
    unsigned short* Cp = Wcombo + (size_t)p*1048576;
    #pragma unroll
    for (int mi = 0; mi < 4; ++mi)
      #pragma unroll
      for (int ni = 0; ni < 4; ++ni)
        #pragma unroll
        for (int j = 0; j < 4; ++j){
          int row = mt*128 + wm*64 + mi*16 + g4*4 + j;
          int col = nb*128 + wn*64 + ni*16 + r15;
          Cp[(size_t)row*512 + col] = f2bf(acc[mi][ni][j]);
        }
  } else {
    const int lj = blockIdx.x - 512;
    const int mt = (lj & 7)*32 + ((lj >> 3) & 31);   // XCD-local A mapping
    const int nb = lj >> 8;
    const unsigned short* ab[4]; const unsigned short* bb[4];
    #pragma unroll
    for (int q = 0; q < 4; ++q){
      int rl = mt*128 + q*32 + w*8 + (lane >> 3);
      ab[q] = embL + (size_t)rl*512 + kc;
      int br = nb*128 + q*32 + w*8 + (lane >> 3);
      bb[q] = Wleaf + (size_t)br*512 + kc;
    }
    f32x4 acc[4][4] = {};
    KLOOP1(ab, bb)
    const int g2 = r15 & 1;
    #pragma unroll
    for (int ni = 0; ni < 4; ++ni){
      int ci = nb*128 + wn*64 + ni*16 + r15;
      float b = bsum[4*(ci >> 1) + (g2 ? 2 : 0)];
      #pragma unroll
      for (int mi = 0; mi < 4; ++mi){
        acc[mi][ni][0]+=b; acc[mi][ni][1]+=b; acc[mi][ni][2]+=b; acc[mi][ni][3]+=b;
      }
    }
    #pragma unroll
    for (int mi = 0; mi < 4; ++mi)
      #pragma unroll
      for (int ni = 0; ni < 4; ++ni){
        f32x4 a0 = acc[mi][ni];
        f32x4 a1 = shfl_xor4(a0, 1);
        f32x4 vi_ = g2 ? a1 : a0;
        f32x4 vg_ = g2 ? a0 : a1;
        int jz = (nb*128 + wn*64 + ni*16 + r15) >> 1;
        #pragma unroll
        for (int u = 0; u < 2; ++u){
          int jrow = (g2 << 1) + u;
          float zi = pick4(vi_, jrow), zg = pick4(vg_, jrow);
          int row = mt*128 + wm*64 + mi*16 + g4*4 + jrow;
          zo[(size_t)row*512 + jz] = f2bf(sigm(zi) * tanh_(zg));
        }
      }
  }
}

// ---------------- fused recurrent step tile (level 4) ----------------
__device__ __forceinline__ void step_core(
    unsigned short* As, unsigned short* Bs,
    const unsigned short* __restrict__ embb,
    const unsigned short* __restrict__ Wcombo,
    const unsigned short* __restrict__ Wih_il,
    const unsigned short* __restrict__ Whh_il,
    const float* __restrict__ bsum, const float* __restrict__ bc,
    const unsigned short* __restrict__ zin, unsigned short* __restrict__ zo,
    const unsigned short* __restrict__ hi, unsigned short* __restrict__ ho,
    float* __restrict__ cbuf, float* __restrict__ outp,
    const int* __restrict__ pm, const int* __restrict__ tp,
    int node_base, int m, int t, int mt, int nbq, int l)
{
  const int tid = threadIdx.x, lane = tid & 63, w = tid >> 6;
  const int wm = w >> 1, wn = w & 1;
  const int r15 = lane & 15, g4 = lane >> 4;
  const int kc = ((lane & 7) ^ (lane >> 3)) * 8;
  const int first = (t == 0), last = (t == 8);
  const int p = tp ? tp[mt] : 0;

  int nn[4];
  #pragma unroll
  for (int q = 0; q < 4; ++q){
    int rl = mt*128 + q*32 + w*8 + (lane >> 3);
    int n = pm ? pm[rl] : (rl < m ? rl : -1);
    nn[q] = (n < 0) ? 0 : n;
  }
  f32x4 acc[4][4] = {};
  { // X phase
    const unsigned short* Bx = (t < 8) ? (Wcombo + (size_t)p*1048576) : Wih_il;
    const unsigned short* ab[4]; const unsigned short* bb[4];
    #pragma unroll
    for (int q = 0; q < 4; ++q){
      ab[q] = (t < 8) ? (zin + ((size_t)nn[q]*8 + t)*512 + kc)
                      : (embb + (size_t)(node_base + nn[q])*512 + kc);
      int br = nbq*128 + q*32 + w*8 + (lane >> 3);
      bb[q] = Bx + (size_t)br*512 + kc;
    }
    KLOOP1(ab, bb)
  }
  if (!first){ // H phase
    const unsigned short* ab[4]; const unsigned short* bb[4];
    #pragma unroll
    for (int q = 0; q < 4; ++q){
      ab[q] = hi + (size_t)nn[q]*512 + kc;
      int br = nbq*128 + q*32 + w*8 + (lane >> 3);
      bb[q] = Whh_il + (size_t)br*512 + kc;
    }
    KLOOP1(ab, bb)
  }
  const int gate = r15 & 3;
  #pragma unroll
  for (int ni = 0; ni < 4; ++ni){
    int ci = nbq*128 + wn*64 + ni*16 + r15;
    float b = bsum[ci] + ((t < 8) ? bc[(size_t)p*2048 + ci] : 0.0f);
    #pragma unroll
    for (int mi = 0; mi < 4; ++mi){
      acc[mi][ni][0]+=b; acc[mi][ni][1]+=b; acc[mi][ni][2]+=b; acc[mi][ni][3]+=b;
    }
  }
  const int jr = r15 & 3;
  #pragma unroll
  for (int mi = 0; mi < 4; ++mi){
    int rl = mt*128 + wm*64 + mi*16 + g4*4 + jr;
    int n = pm ? pm[rl] : (rl < m ? rl : -1);
    #pragma unroll
    for (int ni = 0; ni < 4; ++ni){
      f32x4 a0 = acc[mi][ni];
      f32x4 a1 = shfl_xor4(a0, 1);
      f32x4 a2 = shfl_xor4(a0, 2);
      f32x4 a3 = shfl_xor4(a1, 2);
      f32x4 vi_ = sel4(a0,a1,a2,a3, gate);
      f32x4 vf_ = sel4(a0,a1,a2,a3, gate^1);
      f32x4 vg_ = sel4(a0,a1,a2,a3, gate^2);
      f32x4 vo_ = sel4(a0,a1,a2,a3, gate^3);
      float xi = pick4(vi_, jr), xf = pick4(vf_, jr);
      float xg = pick4(vg_, jr), xo = pick4(vo_, jr);
      if (n >= 0){
        int jz = nbq*32 + wn*16 + ni*4 + (r15 >> 2);
        size_t idx = (size_t)n*512 + jz;
        float i_ = sigm(xi), f_ = sigm(xf), g_ = tanh_(xg), o_ = sigm(xo);
        float cold = first ? 0.0f : cbuf[idx];
        float cn = fmaf(f_, cold, i_*g_);
        if (!last){ cbuf[idx] = cn; ho[idx] = f2bf(o_*tanh_(cn)); }
        else { if (l > 0) zo[idx] = f2bf(cn); else outp[idx] = cn; }
      }
    }
  }
}

// ---- launched step (level 4): col-major jobs + XCD chunking ----
__global__ __launch_bounds__(256) void step_kernel(
    const unsigned short* __restrict__ embb,
    const unsigned short* __restrict__ Wcombo,
    const unsigned short* __restrict__ Wih_il,
    const unsigned short* __restrict__ Whh_il,
    const float* __restrict__ bsum, const float* __restrict__ bc,
    const unsigned short* __restrict__ zin, unsigned short* __restrict__ zo,
    const unsigned short* __restrict__ hi, unsigned short* __restrict__ ho,
    float* __restrict__ cbuf, float* __restrict__ outp,
    const int* __restrict__ perm_t, const int* __restrict__ tile_t,
    const int* __restrict__ meta_t,
    int fixed_nt, int MTcap, int node_base, int m, int t, int l)
{
  __shared__ unsigned short As[8192];
  __shared__ unsigned short Bs[8192];
  int ntiles = meta_t ? *meta_t : fixed_nt;
  if (ntiles > MTcap) ntiles = MTcap;
  const int njobs = ntiles * 16;
  const int chunk = (njobs + 7) >> 3;
  const int g = blockIdx.x & 7, i = blockIdx.x >> 3;
  const int job = g*chunk + i;
  if (i >= chunk || job >= njobs) return;
  const int mt = job % ntiles, nbq = job / ntiles;
  step_core(As, Bs, embb, Wcombo, Wih_il, Whh_il, bsum, bc, zin, zo, hi, ho,
            cbuf, outp, perm_t, tile_t, node_base, m, t, mt, nbq, l);
}

// ---- gatex16: X-gates via 16-row type-group MFMA tiles (levels 3..0) ----
__global__ __launch_bounds__(256) void gatex16(
    const unsigned short* __restrict__ embb,
    const unsigned short* __restrict__ Wcombo,
    const unsigned short* __restrict__ Wih_il,
    const float* __restrict__ bsum, const float* __restrict__ bc,
    const unsigned short* __restrict__ zin,
    half_t* __restrict__ gx, unsigned short* __restrict__ h0out,
    float* __restrict__ cbuf,
    const int* __restrict__ perm16l, const int* __restrict__ tile16l,
    const int* __restrict__ meta16l,
    int MT, int m, int node_base)
{
  __shared__ unsigned short As[1024];   // 16 x 64
  __shared__ unsigned short Bs[8192];   // 128 x 64
  const int jt = blockIdx.x >> 4, cb = blockIdx.x & 15;
  int t, mt, p = 0;
  const int* pm = nullptr;
  if (jt < 8*MT){
    t = jt / MT; mt = jt - t*MT;
    if (mt >= meta16l[t]) return;
    pm = perm16l + t*MT*16;
    p = tile16l[t*MT + mt];
  } else {
    t = 8; mt = jt - 8*MT;
  }
  const int tid = threadIdx.x, lane = tid & 63, w = tid >> 6;
  const int r15 = lane & 15, g4 = lane >> 4;
  const int kc = ((lane & 7) ^ (lane >> 3)) * 8;

  const unsigned short* aptr = nullptr;
  if (w < 2){
    int lr = w*8 + (lane >> 3);
    int n;
    if (t < 8) n = pm[mt*16 + lr];
    else { int r = mt*16 + lr; n = (r < m) ? r : -1; }
    if (n < 0) n = 0;
    const unsigned short* base = (t < 8) ? (zin + ((size_t)n*8 + t)*512)
                                         : (embb + (size_t)(node_base + n)*512);
    aptr = base + (((lane & 7) ^ (lr & 7)) * 8);
  }
  const unsigned short* BxP = (t < 8) ? (Wcombo + (size_t)p*1048576) : Wih_il;
  const unsigned short* bb[4];
  #pragma unroll
  for (int q = 0; q < 4; ++q)
    bb[q] = BxP + (size_t)(cb*128 + q*32 + w*8 + (lane >> 3))*512 + kc;

  f32x4 acc[2] = {};
  for (int kt = 0; kt < 8; ++kt){
    if (w < 2) gload16(aptr + kt*64, As + w*512);
    #pragma unroll
    for (int q = 0; q < 4; ++q)
      gload16(bb[q] + kt*64, Bs + (q*32 + w*8)*64);
    __syncthreads();
    #pragma unroll
    for (int kk = 0; kk < 2; ++kk){
      short8 a = *(const short8*)&As[r15*64 + (((kk*4 + g4) ^ (r15 & 7))*8)];
      #pragma unroll
      for (int ni = 0; ni < 2; ++ni){
        short8 b = *(const short8*)&Bs[(w*32 + ni*16 + r15)*64 + (((kk*4 + g4) ^ (r15 & 7))*8)];
        acc[ni] = mfma16(a, b, acc[ni]);
      }
    }
    __syncthreads();
  }

  #pragma unroll
  for (int ni = 0; ni < 2; ++ni){
    int ci = cb*128 + w*32 + ni*16 + r15;
    float b = bsum[ci] + ((t < 8) ? bc[(size_t)p*2048 + ci] : 0.0f);
    acc[ni][0]+=b; acc[ni][1]+=b; acc[ni][2]+=b; acc[ni][3]+=b;
  }

  if (t == 0){
    const int gate = r15 & 3;
    const int jr = r15 & 3;
    const int lr = g4*4 + jr;
    const int n = pm[mt*16 + lr];
    #pragma unroll
    for (int ni = 0; ni < 2; ++ni){
      f32x4 a0 = acc[ni];
      f32x4 a1 = shfl_xor4(a0, 1);
      f32x4 a2 = shfl_xor4(a0, 2);
      f32x4 a3 = shfl_xor4(a1, 2);
      f32x4 vi_ = sel4(a0,a1,a2,a3, gate);
      f32x4 vg_ = sel4(a0,a1,a2,a3, gate^2);
      f32x4 vo_ = sel4(a0,a1,a2,a3, gate^3);
      float xi = pick4(vi_, jr);
      float xg = pick4(vg_, jr);
      float xo = pick4(vo_, jr);
      if (n >= 0){
        int jz = cb*32 + w*8 + ni*4 + (r15 >> 2);
        size_t idx = (size_t)n*512 + jz;
        float cn = sigm(xi) * tanh_(xg);
        cbuf[idx] = cn;
        h0out[idx] = f2bf(sigm(xo) * tanh_(cn));
      }
    }
  } else {
    #pragma unroll
    for (int ni = 0; ni < 2; ++ni){
      int ci = cb*128 + w*32 + ni*16 + r15;
      #pragma unroll
      for (int j = 0; j < 4; ++j){
        int lr = g4*4 + j;
        int n = (t < 8) ? pm[mt*16 + lr]
                        : ((mt*16 + lr < m) ? mt*16 + lr : -1);
        if (n >= 0) gx[((size_t)t*m + n)*2048 + ci] = (half_t)acc[ni][j];
      }
    }
  }
}

// ---- hstep: launched H-only step (levels 3..0, t=1..8) ----
__global__ __launch_bounds__(256) void hstep_kernel(
    const unsigned short* __restrict__ Whh_il,
    const half_t* __restrict__ gx,
    const unsigned short* __restrict__ hi, unsigned short* __restrict__ ho,
    float* __restrict__ cbuf,
    unsigned short* __restrict__ zo, float* __restrict__ outp,
    int m, int t, int last)
{
  __shared__ unsigned short As[8192];
  __shared__ unsigned short Bs[8192];
  const int mt = blockIdx.x >> 4, nbq = blockIdx.x & 15;
  const int tid = threadIdx.x, lane = tid & 63, w = tid >> 6;
  const int wm = w >> 1, wn = w & 1;
  const int r15 = lane & 15, g4 = lane >> 4;
  const int kc = ((lane & 7) ^ (lane >> 3)) * 8;

  int nn[4];
  #pragma unroll
  for (int q = 0; q < 4; ++q){
    int rl = mt*128 + q*32 + w*8 + (lane >> 3);
    nn[q] = (rl < m) ? rl : 0;
  }
  const unsigned short* ab[4]; const unsigned short* bb[4];
  #pragma unroll
  for (int q = 0; q < 4; ++q){
    ab[q] = hi + (size_t)nn[q]*512 + kc;
    int br = nbq*128 + q*32 + w*8 + (lane >> 3);
    bb[q] = Whh_il + (size_t)br*512 + kc;
  }
  f32x4 acc[4][4] = {};
  KLOOP1(ab, bb)

  #pragma unroll
  for (int mi = 0; mi < 4; ++mi)
    #pragma unroll
    for (int ni = 0; ni < 4; ++ni){
      int ci = nbq*128 + wn*64 + ni*16 + r15;
      #pragma unroll
      for (int j = 0; j < 4; ++j){
        int rl = mt*128 + wm*64 + mi*16 + g4*4 + j;
        if (rl < m) acc[mi][ni][j] += (float)gx[((size_t)t*m + rl)*2048 + ci];
      }
    }

  const int gate = r15 & 3;
  const int jr = r15 & 3;
  #pragma unroll
  for (int mi = 0; mi < 4; ++mi){
    int rl = mt*128 + wm*64 + mi*16 + g4*4 + jr;
    int n = (rl < m) ? rl : -1;
    #pragma unroll
    for (int ni = 0; ni < 4; ++ni){
      f32x4 a0 = acc[mi][ni];
      f32x4 a1 = shfl_xor4(a0, 1);
      f32x4 a2 = shfl_xor4(a0, 2);
      f32x4 a3 = shfl_xor4(a1, 2);
      f32x4 vi_ = sel4(a0,a1,a2,a3, gate);
      f32x4 vf_ = sel4(a0,a1,a2,a3, gate^1);
      f32x4 vg_ = sel4(a0,a1,a2,a3, gate^2);
      f32x4 vo_ = sel4(a0,a1,a2,a3, gate^3);
      float xi = pick4(vi_, jr), xf = pick4(vf_, jr);
      float xg = pick4(vg_, jr), xo = pick4(vo_, jr);
      if (n >= 0){
        int jz = nbq*32 + wn*16 + ni*4 + (r15 >> 2);
        size_t idx = (size_t)n*512 + jz;
        float i_ = sigm(xi), f_ = sigm(xf), g_ = tanh_(xg), o_ = sigm(xo);
        float cn = fmaf(f_, cbuf[idx], i_*g_);
        if (!last){ cbuf[idx] = cn; ho[idx] = f2bf(o_*tanh_(cn)); }
        else { if (zo) zo[idx] = f2bf(cn); else outp[idx] = cn; }
      }
    }
  }
}

// OFF = {0, 1, 9, 73, 585, 4681, 37449}
extern "C" void kernel_launch(void* const* d_in, const int* in_sizes, int n_in,
                              void* d_out, int out_size, void* d_ws, size_t ws_size,
                              hipStream_t stream)
{
  (void)in_sizes; (void)n_in; (void)out_size; (void)ws_size;
  const float* emb   = (const float*)d_in[0];
  const int*   dep   = (const int*)  d_in[1];
  const float* W_dep = (const float*)d_in[2];
  const float* b_dep = (const float*)d_in[3];
  const float* W_ih  = (const float*)d_in[4];
  const float* W_hh  = (const float*)d_in[5];
  const float* b_ih  = (const float*)d_in[6];
  const float* b_hh  = (const float*)d_in[7];
  float* out = (float*)d_out;

  unsigned short* embb   = (unsigned short*)d_ws;                  // 37449*512
  unsigned short* Wih_il = embb   + 19173888ull;                   // 2048*512
  unsigned short* Whh_il = Wih_il + 1048576ull;                    // 2048*512
  unsigned short* Wleaf  = Whh_il + 1048576ull;                    // 1024*512
  unsigned short* WdT    = Wleaf  + 524288ull;                     // 8*512*512
  unsigned short* Wcombo = WdT    + 2097152ull;                    // 8*2048*512
  unsigned short* Z0     = Wcombo + 8388608ull;                    // 32768*512
  unsigned short* Z1     = Z0     + 16777216ull;                   // 4096*512
  unsigned short* hA     = Z1     + 2097152ull;                    // 4096*512
  unsigned short* hB     = hA     + 2097152ull;                    // 4096*512
  float* cbuf  = (float*)(hB + 2097152ull);                        // 4096*512 f32
  float* bsum  = cbuf + 2097152ull;                                // 2048
  float* bc    = bsum + 2048;                                      // 8*2048
  int*  perm   = (int*)(bc + 16384);                               // 77824
  int*  tile_p = perm + 77824;                                     // 608
  int*  meta   = tile_p + 608;                                     // 40
  int*  perm16 = meta + 40;                                        // 8192
  int*  tile16 = perm16 + 8192;                                    // 512
  int*  meta16 = tile16 + 512;                                     // 32
  half_t* gx   = (half_t*)(meta16 + 32);                           // 9*512*2048 f16

  prep_kernel<<<2960, 256, 0, stream>>>(emb, dep, W_dep, b_dep, W_ih, W_hh, b_ih, b_hh,
                                        embb, Wih_il, Whh_il, Wleaf, WdT, bsum, bc,
                                        perm, tile_p, meta, perm16, tile16, meta16);
  comboleaf_kernel<<<2560, 256, 0, stream>>>(Wih_il, WdT, Wcombo,
                                             embb + (size_t)4681*512, Wleaf, bsum, Z0);

  // level 4: 9 fused launched steps (Z0 -> Z1)
  for (int t = 0; t <= 8; ++t){
    const unsigned short* hi = (t & 1) ? hA : hB;
    unsigned short* ho       = (t & 1) ? hB : hA;
    int grid = (t < 8) ? 40*16 : 32*16;
    step_kernel<<<grid, 256, 0, stream>>>(
        embb, Wcombo, Wih_il, Whh_il, bsum, bc,
        Z0, Z1, hi, ho, cbuf, nullptr,
        (t < 8) ? (perm + t*40*128) : nullptr,
        (t < 8) ? (tile_p + t*40) : nullptr,
        (t < 8) ? (meta + 4*8 + t) : nullptr,
        32, 40, 585, 4096, t, 4);
  }

  // levels 3..0: gatex16 + 8 launched H-only steps per level
  struct LvG { int m, node_base, p16, t16, m16, MT, nt8, mtiles; };
  const LvG LG[4] = {
    {512, 73, 0,    0,   0,  40, 32, 4},   // l=3
    {64,  9,  5120, 320, 8,  8,  4,  1},   // l=2
    {8,   1,  6144, 384, 16, 8,  1,  1},   // l=1
    {1,   0,  7168, 448, 24, 8,  1,  1}};  // l=0
  for (int k = 0; k < 4; ++k){
    const int l = 3 - k;
    const unsigned short* zin = (l & 1) ? Z1 : Z0;
    unsigned short* zo        = (l & 1) ? Z0 : Z1;
    gatex16<<<(8*LG[k].MT + LG[k].nt8)*16, 256, 0, stream>>>(
        embb, Wcombo, Wih_il, bsum, bc, zin, gx, hA, cbuf,
        perm16 + LG[k].p16, tile16 + LG[k].t16, meta16 + LG[k].m16,
        LG[k].MT, LG[k].m, LG[k].node_base);
    for (int t = 1; t <= 8; ++t){
      const unsigned short* hi = (t & 1) ? hA : hB;
      unsigned short* ho       = (t & 1) ? hB : hA;
      hstep_kernel<<<LG[k].mtiles*16, 256, 0, stream>>>(
          Whh_il, gx, hi, ho, cbuf,
          (t == 8 && l > 0) ? zo : nullptr, (l == 0) ? out : nullptr,
          LG[k].m, t, (t == 8));
    }
  }
}

// Round 14
// 1284.988 us; speedup vs baseline: 1.0331x; 1.0331x over previous
//
#include <hip/hip_runtime.h>

typedef __attribute__((ext_vector_type(8))) short short8;
typedef __attribute__((ext_vector_type(4))) float f32x4;
typedef _Float16 half_t;

__device__ __forceinline__ unsigned short f2bf(float x){
  union { float f; unsigned u; } v; v.f = x;
  unsigned r = v.u + 0x7fffu + ((v.u >> 16) & 1u);
  return (unsigned short)(r >> 16);
}
__device__ __forceinline__ float sigm(float x){ return 1.0f / (1.0f + __expf(-x)); }
__device__ __forceinline__ float tanh_(float x){
  float e = __expf(2.0f * x);
  return 1.0f - 2.0f / (e + 1.0f);
}
__device__ __forceinline__ short8 load_bf8_f32(const float* p){
  float4 a = *(const float4*)p;
  float4 b = *(const float4*)(p + 4);
  short8 r;
  r[0]=(short)f2bf(a.x); r[1]=(short)f2bf(a.y); r[2]=(short)f2bf(a.z); r[3]=(short)f2bf(a.w);
  r[4]=(short)f2bf(b.x); r[5]=(short)f2bf(b.y); r[6]=(short)f2bf(b.z); r[7]=(short)f2bf(b.w);
  return r;
}
__device__ __forceinline__ f32x4 mfma16(short8 a, short8 b, f32x4 c){
  return __builtin_amdgcn_mfma_f32_16x16x32_bf16(a, b, c, 0, 0, 0);
}
__device__ __forceinline__ void gload16(const void* g, void* lds){
  __builtin_amdgcn_global_load_lds((const __attribute__((address_space(1))) void*)g,
                                   (__attribute__((address_space(3))) void*)lds, 16, 0, 0);
}
__device__ __forceinline__ f32x4 shfl_xor4(f32x4 v, int m){
  f32x4 r;
  r[0]=__shfl_xor(v[0],m); r[1]=__shfl_xor(v[1],m);
  r[2]=__shfl_xor(v[2],m); r[3]=__shfl_xor(v[3],m);
  return r;
}
__device__ __forceinline__ float pick4(f32x4 v, int k){
  float a = (k&1)? v[1] : v[0];
  float b = (k&1)? v[3] : v[2];
  return (k&2)? b : a;
}
__device__ __forceinline__ f32x4 sel4(f32x4 a0, f32x4 a1, f32x4 a2, f32x4 a3, int k){
  f32x4 x = (k&1)? a1 : a0;
  f32x4 y = (k&1)? a3 : a2;
  return (k&2)? y : x;
}

// ======= 128x128 MFMA GEMM K-loop: single-buffer 2-barrier (m97) + XOR swizzle =======
// Used by throughput-bound kernels (big grids, occupancy regime).
#define KSTAGE1(AB, BB, off)                                                         \
  {                                                                                  \
    _Pragma("unroll")                                                                \
    for (int q = 0; q < 4; ++q){                                                     \
      gload16(AB[q] + (off), As + (q*32 + w*8)*64);                                  \
      gload16(BB[q] + (off), Bs + (q*32 + w*8)*64);                                  \
    }                                                                                \
  }

#define KCOMP1                                                                       \
  {                                                                                  \
    _Pragma("unroll")                                                                \
    for (int kk = 0; kk < 2; ++kk){                                                  \
      short8 av[4], bv[4];                                                           \
      _Pragma("unroll")                                                              \
      for (int i = 0; i < 4; ++i)                                                    \
        av[i] = *(const short8*)&As[(wm*64 + i*16 + r15)*64 + (((kk*4 + g4) ^ (r15 & 7))*8)]; \
      _Pragma("unroll")                                                              \
      for (int i = 0; i < 4; ++i)                                                    \
        bv[i] = *(const short8*)&Bs[(wn*64 + i*16 + r15)*64 + (((kk*4 + g4) ^ (r15 & 7))*8)]; \
      _Pragma("unroll")                                                              \
      for (int i = 0; i < 4; ++i)                                                    \
        _Pragma("unroll")                                                            \
        for (int j = 0; j < 4; ++j) acc[i][j] = mfma16(av[i], bv[j], acc[i][j]);     \
    }                                                                                \
  }

#define KLOOP1(AB, BB)                                                               \
  for (int kt = 0; kt < 8; ++kt){                                                    \
    KSTAGE1(AB, BB, kt*64)                                                           \
    __syncthreads();                                                                 \
    KCOMP1                                                                           \
    __syncthreads();                                                                 \
  }

// ======= 2-phase double-buffered K-loop (r8-verified): latency-bound small grids =======
#define KSTAGE2(par, AB, BB, off)                                                    \
  {                                                                                  \
    _Pragma("unroll")                                                                \
    for (int q = 0; q < 4; ++q){                                                     \
      gload16(AB[q] + (off), As + (par)*8192 + (q*32 + w*8)*64);                     \
      gload16(BB[q] + (off), Bs + (par)*8192 + (q*32 + w*8)*64);                     \
    }                                                                                \
  }

#define KCOMP2(par)                                                                  \
  {                                                                                  \
    unsigned short* Ac = As + (par)*8192;                                            \
    unsigned short* Bc = Bs + (par)*8192;                                            \
    _Pragma("unroll")                                                                \
    for (int kk = 0; kk < 2; ++kk){                                                  \
      short8 av[4], bv[4];                                                           \
      _Pragma("unroll")                                                              \
      for (int i = 0; i < 4; ++i)                                                    \
        av[i] = *(const short8*)&Ac[(wm*64 + i*16 + r15)*64 + (((kk*4 + g4) ^ (r15 & 7))*8)]; \
      _Pragma("unroll")                                                              \
      for (int i = 0; i < 4; ++i)                                                    \
        bv[i] = *(const short8*)&Bc[(wn*64 + i*16 + r15)*64 + (((kk*4 + g4) ^ (r15 & 7))*8)]; \
      _Pragma("unroll")                                                              \
      for (int i = 0; i < 4; ++i)                                                    \
        _Pragma("unroll")                                                            \
        for (int j = 0; j < 4; ++j) acc[i][j] = mfma16(av[i], bv[j], acc[i][j]);     \
    }                                                                                \
  }

#define KLOOP2(AB, BB)                                                               \
  {                                                                                  \
    KSTAGE2(0, AB, BB, 0)                                                            \
    __syncthreads();                                                                 \
    for (int kt = 0; kt < 8; ++kt){                                                  \
      if (kt < 7){ KSTAGE2((kt+1)&1, AB, BB, (kt+1)*64) }                            \
      KCOMP2(kt&1)                                                                   \
      __syncthreads();                                                               \
    }                                                                                \
  }

// ---------------- prep: converts, remaps, transpose, bias folds, sorts ----------------
__global__ __launch_bounds__(256) void prep_kernel(
    const float* __restrict__ emb, const int* __restrict__ dep,
    const float* __restrict__ W_dep, const float* __restrict__ b_dep,
    const float* __restrict__ W_ih, const float* __restrict__ W_hh,
    const float* __restrict__ b_ih, const float* __restrict__ b_hh,
    unsigned short* __restrict__ embb, unsigned short* __restrict__ Wih_il,
    unsigned short* __restrict__ Whh_il, unsigned short* __restrict__ Wleaf,
    unsigned short* __restrict__ WdT, float* __restrict__ bsum, float* __restrict__ bc,
    int* __restrict__ perm, int* __restrict__ tile_p, int* __restrict__ meta,
    int* __restrict__ perm16, int* __restrict__ tile16, int* __restrict__ meta16)
{
  const int bid = blockIdx.x, tid = threadIdx.x;
  if (bid < 1024){
    for (size_t i = (size_t)bid*256 + tid; i < 2396736ull; i += 1024ull*256)
      *(short8*)(embb + i*8) = load_bf8_f32(emb + i*8);
  } else if (bid < 1536){
    int idx = (bid-1024)*256 + tid; int r = idx >> 6, c8 = idx & 63;
    int sr = (r & 3)*512 + (r >> 2);
    *(short8*)(Wih_il + (size_t)r*512 + c8*8) = load_bf8_f32(W_ih + (size_t)sr*512 + c8*8);
  } else if (bid < 2048){
    int idx = (bid-1536)*256 + tid; int r = idx >> 6, c8 = idx & 63;
    int sr = (r & 3)*512 + (r >> 2);
    *(short8*)(Whh_il + (size_t)r*512 + c8*8) = load_bf8_f32(W_hh + (size_t)sr*512 + c8*8);
  } else if (bid < 2304){
    int idx = (bid-2048)*256 + tid; int r = idx >> 6, c8 = idx & 63;
    int sr = ((r & 1) ? 2 : 0)*512 + (r >> 1);
    *(short8*)(Wleaf + (size_t)r*512 + c8*8) = load_bf8_f32(W_ih + (size_t)sr*512 + c8*8);
  } else if (bid < 2816){
    __shared__ unsigned short tle[64][65];
    int lb = bid - 2304; int p = lb >> 6; int tile = lb & 63;
    int i0 = (tile >> 3)*64, j0 = (tile & 7)*64;
    const float* src = W_dep + (size_t)p*512*512;
    for (int q = 0; q < 16; ++q){
      int e = q*256 + tid; int li = e >> 6, lj = e & 63;
      tle[li][lj] = f2bf(src[(size_t)(i0+li)*512 + (j0+lj)]);
    }
    __syncthreads();
    unsigned short* dst = WdT + (size_t)p*512*512;
    for (int q = 0; q < 16; ++q){
      int e = q*256 + tid; int lj = e >> 6, li = e & 63;
      dst[(size_t)(j0+lj)*512 + (i0+li)] = tle[li][lj];
    }
  } else if (bid < 2824){
    int r = (bid-2816)*256 + tid;
    if (r < 2048){ int g = r & 3, j = r >> 2; bsum[r] = b_ih[g*512+j] + b_hh[g*512+j]; }
  } else if (bid < 2888){
    __shared__ float bd[512];
    int lb = bid - 2824; int p = lb >> 3, ch = lb & 7;
    for (int i = tid; i < 512; i += 256) bd[i] = b_dep[p*512 + i];
    __syncthreads();
    int r = ch*256 + tid; int g = r & 3, j = r >> 2;
    const float* wr = W_ih + (size_t)(g*512 + j)*512;
    float s = 0.0f;
    for (int i = 0; i < 512; ++i) s = fmaf(wr[i], bd[i], s);
    bc[(size_t)p*2048 + r] = s;
  } else if (bid < 2928){
    __shared__ int cnt[8], base[8], fill[8];
    int lb = bid - 2888; const int l = lb >> 3, t = lb & 7;
    const int M_[5]  = {1,8,64,512,4096};
    const int CB_[5] = {1,9,73,585,4681};
    const int MT_[5] = {8,8,8,12,40};
    const int PB_[5] = {69632,61440,53248,40960,0};
    const int TB_[5] = {544,480,416,320,0};
    const int m = M_[l], cb = CB_[l], MT = MT_[l];
    int* pm = perm + PB_[l] + t*MT*128;
    int* tp = tile_p + TB_[l] + t*MT;
    if (tid < 8){ cnt[tid] = 0; fill[tid] = 0; }
    __syncthreads();
    for (int n = tid; n < m; n += 256) atomicAdd(&cnt[dep[cb + n*8 + t]], 1);
    __syncthreads();
    if (tid == 0){
      int tiles = 0;
      for (int p = 0; p < 8; ++p){
        base[p] = tiles*128;
        int g = (cnt[p] + 127) >> 7;
        for (int q = 0; q < g; ++q) tp[tiles + q] = p;
        tiles += g;
      }
      meta[l*8 + t] = tiles;
    }
    __syncthreads();
    for (int i = tid; i < MT*128; i += 256) pm[i] = -1;
    __syncthreads();
    for (int n = tid; n < m; n += 256){
      int p = dep[cb + n*8 + t];
      pm[base[p] + atomicAdd(&fill[p], 1)] = n;
    }
  } else {
    // 16-row type-group sort for levels 3..0 (li: 0=l3, 1=l2, 2=l1, 3=l0)
    __shared__ int cnt[8], base[8], fill[8];
    int lb = bid - 2928; const int li = lb >> 3, t = lb & 7;
    const int M_[4]  = {512,64,8,1};
    const int CB_[4] = {585,73,9,1};
    const int MT_[4] = {40,8,8,8};
    const int PB_[4] = {0, 5120, 6144, 7168};
    const int TB_[4] = {0, 320, 384, 448};
    const int m = M_[li], cbb = CB_[li], MT = MT_[li];
    int* pm = perm16 + PB_[li] + t*MT*16;
    int* tp = tile16 + TB_[li] + t*MT;
    if (tid < 8){ cnt[tid] = 0; fill[tid] = 0; }
    __syncthreads();
    for (int n = tid; n < m; n += 256) atomicAdd(&cnt[dep[cbb + n*8 + t]], 1);
    __syncthreads();
    if (tid == 0){
      int tiles = 0;
      for (int p = 0; p < 8; ++p){
        base[p] = tiles*16;
        int g = (cnt[p] + 15) >> 4;
        for (int q = 0; q < g; ++q) tp[tiles + q] = p;
        tiles += g;
      }
      meta16[li*8 + t] = tiles;
    }
    __syncthreads();
    for (int i = tid; i < MT*16; i += 256) pm[i] = -1;
    __syncthreads();
    for (int n = tid; n < m; n += 256){
      int p = dep[cbb + n*8 + t];
      pm[base[p] + atomicAdd(&fill[p], 1)] = n;
    }
  }
}

// ---- fused one-time GEMMs: Wcombo (jobs 0..511) + leaf (jobs 512..2559) ----
__global__ __launch_bounds__(256) void comboleaf_kernel(
    const unsigned short* __restrict__ Wih_il,
    const unsigned short* __restrict__ WdT,
    unsigned short* __restrict__ Wcombo,
    const unsigned short* __restrict__ embL,
    const unsigned short* __restrict__ Wleaf,
    const float* __restrict__ bsum,
    unsigned short* __restrict__ zo)
{
  __shared__ unsigned short As[8192];
  __shared__ unsigned short Bs[8192];
  const int tid = threadIdx.x, lane = tid & 63, w = tid >> 6;
  const int wm = w >> 1, wn = w & 1;
  const int r15 = lane & 15, g4 = lane >> 4;
  const int kc = ((lane & 7) ^ (lane >> 3)) * 8;

  if (blockIdx.x < 512){
    const int p  = blockIdx.x >> 6;
    const int mt = (blockIdx.x >> 2) & 15;
    const int nb = blockIdx.x & 3;
    const unsigned short* ab[4]; const unsigned short* bb[4];
    #pragma unroll
    for (int q = 0; q < 4; ++q){
      int rl = mt*128 + q*32 + w*8 + (lane >> 3);
      ab[q] = Wih_il + (size_t)rl*512 + kc;
      int br = nb*128 + q*32 + w*8 + (lane >> 3);
      bb[q] = WdT + (size_t)p*262144 + (size_t)br*512 + kc;
    }
    f32x4 acc[4][4] = {};
    KLOOP1(ab, bb)
    unsigned short* Cp = Wcombo + (size_t)p*1048576;
    #pragma unroll
    for (int mi = 0; mi < 4; ++mi)
      #pragma unroll
      for (int ni = 0; ni < 4; ++ni)
        #pragma unroll
        for (int j = 0; j < 4; ++j){
          int row = mt*128 + wm*64 + mi*16 + g4*4 + j;
          int col = nb*128 + wn*64 + ni*16 + r15;
          Cp[(size_t)row*512 + col] = f2bf(acc[mi][ni][j]);
        }
  } else {
    const int lj = blockIdx.x - 512;
    const int mt = (lj & 7)*32 + ((lj >> 3) & 31);   // XCD-local A mapping
    const int nb = lj >> 8;
    const unsigned short* ab[4]; const unsigned short* bb[4];
    #pragma unroll
    for (int q = 0; q < 4; ++q){
      int rl = mt*128 + q*32 + w*8 + (lane >> 3);
      ab[q] = embL + (size_t)rl*512 + kc;
      int br = nb*128 + q*32 + w*8 + (lane >> 3);
      bb[q] = Wleaf + (size_t)br*512 + kc;
    }
    f32x4 acc[4][4] = {};
    KLOOP1(ab, bb)
    const int g2 = r15 & 1;
    #pragma unroll
    for (int ni = 0; ni < 4; ++ni){
      int ci = nb*128 + wn*64 + ni*16 + r15;
      float b = bsum[4*(ci >> 1) + (g2 ? 2 : 0)];
      #pragma unroll
      for (int mi = 0; mi < 4; ++mi){
        acc[mi][ni][0]+=b; acc[mi][ni][1]+=b; acc[mi][ni][2]+=b; acc[mi][ni][3]+=b;
      }
    }
    #pragma unroll
    for (int mi = 0; mi < 4; ++mi)
      #pragma unroll
      for (int ni = 0; ni < 4; ++ni){
        f32x4 a0 = acc[mi][ni];
        f32x4 a1 = shfl_xor4(a0, 1);
        f32x4 vi_ = g2 ? a1 : a0;
        f32x4 vg_ = g2 ? a0 : a1;
        int jz = (nb*128 + wn*64 + ni*16 + r15) >> 1;
        #pragma unroll
        for (int u = 0; u < 2; ++u){
          int jrow = (g2 << 1) + u;
          float zi = pick4(vi_, jrow), zg = pick4(vg_, jrow);
          int row = mt*128 + wm*64 + mi*16 + g4*4 + jrow;
          zo[(size_t)row*512 + jz] = f2bf(sigm(zi) * tanh_(zg));
        }
      }
  }
}

// ---------------- fused recurrent step tile (level 4) ----------------
__device__ __forceinline__ void step_core(
    unsigned short* As, unsigned short* Bs,
    const unsigned short* __restrict__ embb,
    const unsigned short* __restrict__ Wcombo,
    const unsigned short* __restrict__ Wih_il,
    const unsigned short* __restrict__ Whh_il,
    const float* __restrict__ bsum, const float* __restrict__ bc,
    const unsigned short* __restrict__ zin, unsigned short* __restrict__ zo,
    const unsigned short* __restrict__ hi, unsigned short* __restrict__ ho,
    float* __restrict__ cbuf, float* __restrict__ outp,
    const int* __restrict__ pm, const int* __restrict__ tp,
    int node_base, int m, int t, int mt, int nbq, int l)
{
  const int tid = threadIdx.x, lane = tid & 63, w = tid >> 6;
  const int wm = w >> 1, wn = w & 1;
  const int r15 = lane & 15, g4 = lane >> 4;
  const int kc = ((lane & 7) ^ (lane >> 3)) * 8;
  const int first = (t == 0), last = (t == 8);
  const int p = tp ? tp[mt] : 0;

  int nn[4];
  #pragma unroll
  for (int q = 0; q < 4; ++q){
    int rl = mt*128 + q*32 + w*8 + (lane >> 3);
    int n = pm ? pm[rl] : (rl < m ? rl : -1);
    nn[q] = (n < 0) ? 0 : n;
  }
  f32x4 acc[4][4] = {};
  { // X phase
    const unsigned short* Bx = (t < 8) ? (Wcombo + (size_t)p*1048576) : Wih_il;
    const unsigned short* ab[4]; const unsigned short* bb[4];
    #pragma unroll
    for (int q = 0; q < 4; ++q){
      ab[q] = (t < 8) ? (zin + ((size_t)nn[q]*8 + t)*512 + kc)
                      : (embb + (size_t)(node_base + nn[q])*512 + kc);
      int br = nbq*128 + q*32 + w*8 + (lane >> 3);
      bb[q] = Bx + (size_t)br*512 + kc;
    }
    KLOOP1(ab, bb)
  }
  if (!first){ // H phase
    const unsigned short* ab[4]; const unsigned short* bb[4];
    #pragma unroll
    for (int q = 0; q < 4; ++q){
      ab[q] = hi + (size_t)nn[q]*512 + kc;
      int br = nbq*128 + q*32 + w*8 + (lane >> 3);
      bb[q] = Whh_il + (size_t)br*512 + kc;
    }
    KLOOP1(ab, bb)
  }
  const int gate = r15 & 3;
  #pragma unroll
  for (int ni = 0; ni < 4; ++ni){
    int ci = nbq*128 + wn*64 + ni*16 + r15;
    float b = bsum[ci] + ((t < 8) ? bc[(size_t)p*2048 + ci] : 0.0f);
    #pragma unroll
    for (int mi = 0; mi < 4; ++mi){
      acc[mi][ni][0]+=b; acc[mi][ni][1]+=b; acc[mi][ni][2]+=b; acc[mi][ni][3]+=b;
    }
  }
  const int jr = r15 & 3;
  #pragma unroll
  for (int mi = 0; mi < 4; ++mi){
    int rl = mt*128 + wm*64 + mi*16 + g4*4 + jr;
    int n = pm ? pm[rl] : (rl < m ? rl : -1);
    #pragma unroll
    for (int ni = 0; ni < 4; ++ni){
      f32x4 a0 = acc[mi][ni];
      f32x4 a1 = shfl_xor4(a0, 1);
      f32x4 a2 = shfl_xor4(a0, 2);
      f32x4 a3 = shfl_xor4(a1, 2);
      f32x4 vi_ = sel4(a0,a1,a2,a3, gate);
      f32x4 vf_ = sel4(a0,a1,a2,a3, gate^1);
      f32x4 vg_ = sel4(a0,a1,a2,a3, gate^2);
      f32x4 vo_ = sel4(a0,a1,a2,a3, gate^3);
      float xi = pick4(vi_, jr), xf = pick4(vf_, jr);
      float xg = pick4(vg_, jr), xo = pick4(vo_, jr);
      if (n >= 0){
        int jz = nbq*32 + wn*16 + ni*4 + (r15 >> 2);
        size_t idx = (size_t)n*512 + jz;
        float i_ = sigm(xi), f_ = sigm(xf), g_ = tanh_(xg), o_ = sigm(xo);
        float cold = first ? 0.0f : cbuf[idx];
        float cn = fmaf(f_, cold, i_*g_);
        if (!last){ cbuf[idx] = cn; ho[idx] = f2bf(o_*tanh_(cn)); }
        else { if (l > 0) zo[idx] = f2bf(cn); else outp[idx] = cn; }
      }
    }
  }
}

// ---- launched step (level 4): col-major jobs + XCD chunking ----
__global__ __launch_bounds__(256) void step_kernel(
    const unsigned short* __restrict__ embb,
    const unsigned short* __restrict__ Wcombo,
    const unsigned short* __restrict__ Wih_il,
    const unsigned short* __restrict__ Whh_il,
    const float* __restrict__ bsum, const float* __restrict__ bc,
    const unsigned short* __restrict__ zin, unsigned short* __restrict__ zo,
    const unsigned short* __restrict__ hi, unsigned short* __restrict__ ho,
    float* __restrict__ cbuf, float* __restrict__ outp,
    const int* __restrict__ perm_t, const int* __restrict__ tile_t,
    const int* __restrict__ meta_t,
    int fixed_nt, int MTcap, int node_base, int m, int t, int l)
{
  __shared__ unsigned short As[8192];
  __shared__ unsigned short Bs[8192];
  int ntiles = meta_t ? *meta_t : fixed_nt;
  if (ntiles > MTcap) ntiles = MTcap;
  const int njobs = ntiles * 16;
  const int chunk = (njobs + 7) >> 3;
  const int g = blockIdx.x & 7, i = blockIdx.x >> 3;
  const int job = g*chunk + i;
  if (i >= chunk || job >= njobs) return;
  const int mt = job % ntiles, nbq = job / ntiles;
  step_core(As, Bs, embb, Wcombo, Wih_il, Whh_il, bsum, bc, zin, zo, hi, ho,
            cbuf, outp, perm_t, tile_t, node_base, m, t, mt, nbq, l);
}

// ---- gatex16: X-gates via 16-row type-group MFMA tiles (levels 3..0) ----
// 2-phase double-buffered staging (latency-bound small grids).
__global__ __launch_bounds__(256) void gatex16(
    const unsigned short* __restrict__ embb,
    const unsigned short* __restrict__ Wcombo,
    const unsigned short* __restrict__ Wih_il,
    const float* __restrict__ bsum, const float* __restrict__ bc,
    const unsigned short* __restrict__ zin,
    half_t* __restrict__ gx, unsigned short* __restrict__ h0out,
    float* __restrict__ cbuf,
    const int* __restrict__ perm16l, const int* __restrict__ tile16l,
    const int* __restrict__ meta16l,
    int MT, int m, int node_base)
{
  __shared__ unsigned short As[2048];    // 2 x (16 x 64)
  __shared__ unsigned short Bs[16384];   // 2 x (128 x 64)
  const int jt = blockIdx.x >> 4, cb = blockIdx.x & 15;
  int t, mt, p = 0;
  const int* pm = nullptr;
  if (jt < 8*MT){
    t = jt / MT; mt = jt - t*MT;
    if (mt >= meta16l[t]) return;
    pm = perm16l + t*MT*16;
    p = tile16l[t*MT + mt];
  } else {
    t = 8; mt = jt - 8*MT;
  }
  const int tid = threadIdx.x, lane = tid & 63, w = tid >> 6;
  const int r15 = lane & 15, g4 = lane >> 4;
  const int kc = ((lane & 7) ^ (lane >> 3)) * 8;

  const unsigned short* aptr = nullptr;
  if (w < 2){
    int lr = w*8 + (lane >> 3);
    int n;
    if (t < 8) n = pm[mt*16 + lr];
    else { int r = mt*16 + lr; n = (r < m) ? r : -1; }
    if (n < 0) n = 0;
    const unsigned short* base = (t < 8) ? (zin + ((size_t)n*8 + t)*512)
                                         : (embb + (size_t)(node_base + n)*512);
    aptr = base + (((lane & 7) ^ (lr & 7)) * 8);
  }
  const unsigned short* BxP = (t < 8) ? (Wcombo + (size_t)p*1048576) : Wih_il;
  const unsigned short* bb[4];
  #pragma unroll
  for (int q = 0; q < 4; ++q)
    bb[q] = BxP + (size_t)(cb*128 + q*32 + w*8 + (lane >> 3))*512 + kc;

  f32x4 acc[2] = {};
  // prologue: stage kt=0 into parity 0
  if (w < 2) gload16(aptr, As + w*512);
  #pragma unroll
  for (int q = 0; q < 4; ++q) gload16(bb[q], Bs + (q*32 + w*8)*64);
  __syncthreads();
  for (int kt = 0; kt < 8; ++kt){
    if (kt < 7){
      const int pn = (kt + 1) & 1;
      if (w < 2) gload16(aptr + (kt+1)*64, As + pn*1024 + w*512);
      #pragma unroll
      for (int q = 0; q < 4; ++q)
        gload16(bb[q] + (kt+1)*64, Bs + pn*8192 + (q*32 + w*8)*64);
    }
    const int pc = kt & 1;
    #pragma unroll
    for (int kk = 0; kk < 2; ++kk){
      short8 a = *(const short8*)&As[pc*1024 + r15*64 + (((kk*4 + g4) ^ (r15 & 7))*8)];
      #pragma unroll
      for (int ni = 0; ni < 2; ++ni){
        short8 b = *(const short8*)&Bs[pc*8192 + (w*32 + ni*16 + r15)*64 + (((kk*4 + g4) ^ (r15 & 7))*8)];
        acc[ni] = mfma16(a, b, acc[ni]);
      }
    }
    __syncthreads();
  }

  #pragma unroll
  for (int ni = 0; ni < 2; ++ni){
    int ci = cb*128 + w*32 + ni*16 + r15;
    float b = bsum[ci] + ((t < 8) ? bc[(size_t)p*2048 + ci] : 0.0f);
    acc[ni][0]+=b; acc[ni][1]+=b; acc[ni][2]+=b; acc[ni][3]+=b;
  }

  if (t == 0){
    const int gate = r15 & 3;
    const int jr = r15 & 3;
    const int lr = g4*4 + jr;
    const int n = pm[mt*16 + lr];
    #pragma unroll
    for (int ni = 0; ni < 2; ++ni){
      f32x4 a0 = acc[ni];
      f32x4 a1 = shfl_xor4(a0, 1);
      f32x4 a2 = shfl_xor4(a0, 2);
      f32x4 a3 = shfl_xor4(a1, 2);
      f32x4 vi_ = sel4(a0,a1,a2,a3, gate);
      f32x4 vg_ = sel4(a0,a1,a2,a3, gate^2);
      f32x4 vo_ = sel4(a0,a1,a2,a3, gate^3);
      float xi = pick4(vi_, jr);
      float xg = pick4(vg_, jr);
      float xo = pick4(vo_, jr);
      if (n >= 0){
        int jz = cb*32 + w*8 + ni*4 + (r15 >> 2);
        size_t idx = (size_t)n*512 + jz;
        float cn = sigm(xi) * tanh_(xg);
        cbuf[idx] = cn;
        h0out[idx] = f2bf(sigm(xo) * tanh_(cn));
      }
    }
  } else {
    #pragma unroll
    for (int ni = 0; ni < 2; ++ni){
      int ci = cb*128 + w*32 + ni*16 + r15;
      #pragma unroll
      for (int j = 0; j < 4; ++j){
        int lr = g4*4 + j;
        int n = (t < 8) ? pm[mt*16 + lr]
                        : ((mt*16 + lr < m) ? mt*16 + lr : -1);
        if (n >= 0) gx[((size_t)t*m + n)*2048 + ci] = (half_t)acc[ni][j];
      }
    }
  }
}

// ---- hstep: launched H-only step (levels 3..0, t=1..8); double-buffered ----
__global__ __launch_bounds__(256) void hstep_kernel(
    const unsigned short* __restrict__ Whh_il,
    const half_t* __restrict__ gx,
    const unsigned short* __restrict__ hi, unsigned short* __restrict__ ho,
    float* __restrict__ cbuf,
    unsigned short* __restrict__ zo, float* __restrict__ outp,
    int m, int t, int last)
{
  __shared__ unsigned short As[16384];
  __shared__ unsigned short Bs[16384];
  const int mt = blockIdx.x >> 4, nbq = blockIdx.x & 15;
  const int tid = threadIdx.x, lane = tid & 63, w = tid >> 6;
  const int wm = w >> 1, wn = w & 1;
  const int r15 = lane & 15, g4 = lane >> 4;
  const int kc = ((lane & 7) ^ (lane >> 3)) * 8;

  int nn[4];
  #pragma unroll
  for (int q = 0; q < 4; ++q){
    int rl = mt*128 + q*32 + w*8 + (lane >> 3);
    nn[q] = (rl < m) ? rl : 0;
  }
  const unsigned short* ab[4]; const unsigned short* bb[4];
  #pragma unroll
  for (int q = 0; q < 4; ++q){
    ab[q] = hi + (size_t)nn[q]*512 + kc;
    int br = nbq*128 + q*32 + w*8 + (lane >> 3);
    bb[q] = Whh_il + (size_t)br*512 + kc;
  }
  f32x4 acc[4][4] = {};
  KLOOP2(ab, bb)

  #pragma unroll
  for (int mi = 0; mi < 4; ++mi)
    #pragma unroll
    for (int ni = 0; ni < 4; ++ni){
      int ci = nbq*128 + wn*64 + ni*16 + r15;
      #pragma unroll
      for (int j = 0; j < 4; ++j){
        int rl = mt*128 + wm*64 + mi*16 + g4*4 + j;
        if (rl < m) acc[mi][ni][j] += (float)gx[((size_t)t*m + rl)*2048 + ci];
      }
    }

  const int gate = r15 & 3;
  const int jr = r15 & 3;
  #pragma unroll
  for (int mi = 0; mi < 4; ++mi){
    int rl = mt*128 + wm*64 + mi*16 + g4*4 + jr;
    int n = (rl < m) ? rl : -1;
    #pragma unroll
    for (int ni = 0; ni < 4; ++ni){
      f32x4 a0 = acc[mi][ni];
      f32x4 a1 = shfl_xor4(a0, 1);
      f32x4 a2 = shfl_xor4(a0, 2);
      f32x4 a3 = shfl_xor4(a1, 2);
      f32x4 vi_ = sel4(a0,a1,a2,a3, gate);
      f32x4 vf_ = sel4(a0,a1,a2,a3, gate^1);
      f32x4 vg_ = sel4(a0,a1,a2,a3, gate^2);
      f32x4 vo_ = sel4(a0,a1,a2,a3, gate^3);
      float xi = pick4(vi_, jr), xf = pick4(vf_, jr);
      float xg = pick4(vg_, jr), xo = pick4(vo_, jr);
      if (n >= 0){
        int jz = nbq*32 + wn*16 + ni*4 + (r15 >> 2);
        size_t idx = (size_t)n*512 + jz;
        float i_ = sigm(xi), f_ = sigm(xf), g_ = tanh_(xg), o_ = sigm(xo);
        float cn = fmaf(f_, cbuf[idx], i_*g_);
        if (!last){ cbuf[idx] = cn; ho[idx] = f2bf(o_*tanh_(cn)); }
        else { if (zo) zo[idx] = f2bf(cn); else outp[idx] = cn; }
      }
    }
  }
}

// OFF = {0, 1, 9, 73, 585, 4681, 37449}
extern "C" void kernel_launch(void* const* d_in, const int* in_sizes, int n_in,
                              void* d_out, int out_size, void* d_ws, size_t ws_size,
                              hipStream_t stream)
{
  (void)in_sizes; (void)n_in; (void)out_size; (void)ws_size;
  const float* emb   = (const float*)d_in[0];
  const int*   dep   = (const int*)  d_in[1];
  const float* W_dep = (const float*)d_in[2];
  const float* b_dep = (const float*)d_in[3];
  const float* W_ih  = (const float*)d_in[4];
  const float* W_hh  = (const float*)d_in[5];
  const float* b_ih  = (const float*)d_in[6];
  const float* b_hh  = (const float*)d_in[7];
  float* out = (float*)d_out;

  unsigned short* embb   = (unsigned short*)d_ws;                  // 37449*512
  unsigned short* Wih_il = embb   + 19173888ull;                   // 2048*512
  unsigned short* Whh_il = Wih_il + 1048576ull;                    // 2048*512
  unsigned short* Wleaf  = Whh_il + 1048576ull;                    // 1024*512
  unsigned short* WdT    = Wleaf  + 524288ull;                     // 8*512*512
  unsigned short* Wcombo = WdT    + 2097152ull;                    // 8*2048*512
  unsigned short* Z0     = Wcombo + 8388608ull;                    // 32768*512
  unsigned short* Z1     = Z0     + 16777216ull;                   // 4096*512
  unsigned short* hA     = Z1     + 2097152ull;                    // 4096*512
  unsigned short* hB     = hA     + 2097152ull;                    // 4096*512
  float* cbuf  = (float*)(hB + 2097152ull);                        // 4096*512 f32
  float* bsum  = cbuf + 2097152ull;                                // 2048
  float* bc    = bsum + 2048;                                      // 8*2048
  int*  perm   = (int*)(bc + 16384);                               // 77824
  int*  tile_p = perm + 77824;                                     // 608
  int*  meta   = tile_p + 608;                                     // 40
  int*  perm16 = meta + 40;                                        // 8192
  int*  tile16 = perm16 + 8192;                                    // 512
  int*  meta16 = tile16 + 512;                                     // 32
  half_t* gx   = (half_t*)(meta16 + 32);                           // 9*512*2048 f16

  prep_kernel<<<2960, 256, 0, stream>>>(emb, dep, W_dep, b_dep, W_ih, W_hh, b_ih, b_hh,
                                        embb, Wih_il, Whh_il, Wleaf, WdT, bsum, bc,
                                        perm, tile_p, meta, perm16, tile16, meta16);
  comboleaf_kernel<<<2560, 256, 0, stream>>>(Wih_il, WdT, Wcombo,
                                             embb + (size_t)4681*512, Wleaf, bsum, Z0);

  // level 4: 9 fused launched steps (Z0 -> Z1)
  for (int t = 0; t <= 8; ++t){
    const unsigned short* hi = (t & 1) ? hA : hB;
    unsigned short* ho       = (t & 1) ? hB : hA;
    int grid = (t < 8) ? 40*16 : 32*16;
    step_kernel<<<grid, 256, 0, stream>>>(
        embb, Wcombo, Wih_il, Whh_il, bsum, bc,
        Z0, Z1, hi, ho, cbuf, nullptr,
        (t < 8) ? (perm + t*40*128) : nullptr,
        (t < 8) ? (tile_p + t*40) : nullptr,
        (t < 8) ? (meta + 4*8 + t) : nullptr,
        32, 40, 585, 4096, t, 4);
  }

  // levels 3..0: gatex16 + 8 launched H-only steps per level
  struct LvG { int m, node_base, p16, t16, m16, MT, nt8, mtiles; };
  const LvG LG[4] = {
    {512, 73, 0,    0,   0,  40, 32, 4},   // l=3
    {64,  9,  5120, 320, 8,  8,  4,  1},   // l=2
    {8,   1,  6144, 384, 16, 8,  1,  1},   // l=1
    {1,   0,  7168, 448, 24, 8,  1,  1}};  // l=0
  for (int k = 0; k < 4; ++k){
    const int l = 3 - k;
    const unsigned short* zin = (l & 1) ? Z1 : Z0;
    unsigned short* zo        = (l & 1) ? Z0 : Z1;
    gatex16<<<(8*LG[k].MT + LG[k].nt8)*16, 256, 0, stream>>>(
        embb, Wcombo, Wih_il, bsum, bc, zin, gx, hA, cbuf,
        perm16 + LG[k].p16, tile16 + LG[k].t16, meta16 + LG[k].m16,
        LG[k].MT, LG[k].m, LG[k].node_base);
    for (int t = 1; t <= 8; ++t){
      const unsigned short* hi = (t & 1) ? hA : hB;
      unsigned short* ho       = (t & 1) ? hB : hA;
      hstep_kernel<<<LG[k].mtiles*16, 256, 0, stream>>>(
          Whh_il, gx, hi, ho, cbuf,
          (t == 8 && l > 0) ? zo : nullptr, (l == 0) ? out : nullptr,
          LG[k].m, t, (t == 8));
    }
  }
}